// Round 9
// baseline (5629.892 us; speedup 1.0000x reference)
//
#include <hip/hip_runtime.h>
#include <math.h>

#define B64 64
#define H 1024
#define DD 8
#define ENC 96
#define HOR 336
#define TT 432
#define NSTEP 431
#define NBLK 256
#define KS0 32      // K=1024 in 32-wide chunks
#define KS1 64      // K=2048

typedef __attribute__((ext_vector_type(8))) short short8;
typedef __attribute__((ext_vector_type(4))) float f32x4;
typedef unsigned long long ull;

__device__ __forceinline__ unsigned short f2bf(float x) {
    union { float f; unsigned u; } v; v.f = x;
    unsigned r = v.u + 0x7fffu + ((v.u >> 16) & 1u);
    return (unsigned short)(r >> 16);
}
__device__ __forceinline__ float sigm(float x) {
    return __builtin_amdgcn_rcpf(1.0f + __expf(-x));
}
__device__ __forceinline__ float ftanh(float x) {
    float e = __expf(fminf(x, 10.0f) * 2.0f);   // clamp: avoid inf/inf
    return (e - 1.0f) * __builtin_amdgcn_rcpf(e + 1.0f);
}

// Agent-coherent (sc0 sc1, MALL-coherent, no cache-maintenance) accessors
__device__ __forceinline__ short8 cload(const unsigned short* p) {
    const ull* q = (const ull*)p;
    ull lo = __hip_atomic_load(q,     __ATOMIC_RELAXED, __HIP_MEMORY_SCOPE_AGENT);
    ull hi = __hip_atomic_load(q + 1, __ATOMIC_RELAXED, __HIP_MEMORY_SCOPE_AGENT);
    union { ull u[2]; short8 s; } v; v.u[0] = lo; v.u[1] = hi;
    return v.s;
}
__device__ __forceinline__ void cstore8(ull* p, ull v) {
    __hip_atomic_store(p, v, __ATOMIC_RELAXED, __HIP_MEMORY_SCOPE_AGENT);
}

// ---------------- prep kernels (verified) ----------------

__global__ void zero_k(unsigned int* __restrict__ p, int n) {
    for (int i = blockIdx.x * 256 + threadIdx.x; i < n; i += gridDim.x * 256) p[i] = 0u;
}

__global__ void pack0_k(const float* __restrict__ w, unsigned short* __restrict__ dst) {
    const int total = 128 * 2 * KS0 * 64 * 8;
    for (int idx = blockIdx.x * 256 + threadIdx.x; idx < total; idx += gridDim.x * 256) {
        int j = idx & 7, lane = (idx >> 3) & 63, ks = (idx >> 9) & 31, nt = (idx >> 14) & 1, nb = idx >> 15;
        int rr = nt * 16 + (lane & 15);
        int row = nb * 8 + (rr >> 2) + 1024 * (rr & 3);
        int k = ks * 32 + ((lane >> 4) << 3) + j;
        dst[idx] = f2bf(w[row * 1024 + k]);
    }
}

__global__ void pack1_k(const float* __restrict__ wih, const float* __restrict__ whh,
                        unsigned short* __restrict__ dst) {
    const int total = 128 * 2 * KS1 * 64 * 8;
    for (int idx = blockIdx.x * 256 + threadIdx.x; idx < total; idx += gridDim.x * 256) {
        int j = idx & 7, lane = (idx >> 3) & 63, ks = (idx >> 9) & 63, nt = (idx >> 15) & 1, nb = idx >> 16;
        int rr = nt * 16 + (lane & 15);
        int row = nb * 8 + (rr >> 2) + 1024 * (rr & 3);
        int k = ks * 32 + ((lane >> 4) << 3) + j;
        float v = (k < 1024) ? wih[row * 1024 + k] : whh[row * 1024 + (k - 1024)];
        dst[idx] = f2bf(v);
    }
}

__global__ void pack2_k(const float* __restrict__ w, unsigned short* __restrict__ dst) {
    const int total = 2 * KS0 * 64 * 8;
    for (int idx = blockIdx.x * 256 + threadIdx.x; idx < total; idx += gridDim.x * 256) {
        int j = idx & 7, lane = (idx >> 3) & 63, ks = (idx >> 9) & 31, nt = (idx >> 14) & 1;
        int rr = nt * 16 + (lane & 15);
        int row = (rr >> 2) + 8 * (rr & 3);
        int k = ks * 32 + ((lane >> 4) << 3) + j;
        dst[idx] = f2bf(w[row * 1024 + k]);
    }
}

__global__ void copy_y_k(const float* __restrict__ inp, float* __restrict__ y) {
    const int total = B64 * HOR * DD;
    for (int i = blockIdx.x * 256 + threadIdx.x; i < total; i += gridDim.x * 256) {
        int b = i / (HOR * DD);
        int rem = i - b * (HOR * DD);
        y[i] = inp[b * (TT * DD) + ENC * DD + rem];
    }
}

__global__ void loss_k(const float* __restrict__ pred, const float* __restrict__ y,
                       float* __restrict__ loss) {
    __shared__ float part[256];
    int tid = threadIdx.x;
    int dd = tid & 7, cc = tid >> 3;
    float s = 0.f;
    for (int i = cc; i < B64 * HOR; i += 32) {
        float d = pred[i * 8 + dd] - y[i * 8 + dd];
        s += d * d;
    }
    part[tid] = s;
    __syncthreads();
    if (tid < 8) {
        float t = 0.f;
        for (int r = 0; r < 32; ++r) t += part[r * 8 + tid];
        loss[tid] = t / (float)(B64 * HOR);
    }
}

// ---- grid barrier (round-8, verified): system flags, all-sweep, no sleep ----
__device__ __forceinline__ void gbar(unsigned* dom, int rb, unsigned ep) {
    const int tid = threadIdx.x;
    if (tid < 64) {
        if (tid == 0) {
            __builtin_amdgcn_s_waitcnt(0x0f70);     // vmcnt(0): wave-0 h-stores drained
            __hip_atomic_store(dom + rb * 32, ep, __ATOMIC_RELAXED,
                               __HIP_MEMORY_SCOPE_SYSTEM);
        }
        const unsigned* f0 = dom + tid * 32;
        const unsigned* f1 = dom + (tid + 64) * 32;
        for (;;) {
            unsigned a = __hip_atomic_load(f0, __ATOMIC_RELAXED, __HIP_MEMORY_SCOPE_SYSTEM);
            unsigned b = __hip_atomic_load(f1, __ATOMIC_RELAXED, __HIP_MEMORY_SCOPE_SYSTEM);
            if (__all((a >= ep) && (b >= ep))) break;
        }
    }
    __syncthreads();
}

// ---------------- persistent recurrence kernel ----------------
// Round-9 structure (each h-vector read ONCE per block per step; both windows
// symmetric ~16 loads + 64 MFMA):
//  A->B: load h0(t) quarter -> P2-h0 GEMM (Wr1h0) + P1(t+1) GEMM (Wr0);
//        P2 cell (8-way reduce: h0 part now + h1 part from prev window);
//        publish h1(t); barrier B.
//  B->A: load h1(t) quarter -> P3 GEMM (Wr2) + P2(t+1)-h1 GEMM (Wr1h1);
//        P3 cell -> h2x/pred; P1(t+1) cell (red2 + wih0*x); publish h0(t+1);
//        park P2-h1 partials in red1-upper; barrier A.
__global__ __launch_bounds__(256, 1) void persist_k(
    const unsigned short* __restrict__ Wp0,
    const unsigned short* __restrict__ Wp1,
    const unsigned short* __restrict__ Wp2,
    const float* __restrict__ wih0, const float* __restrict__ b0v,
    const float* __restrict__ b1v,
    const float* __restrict__ whh2, const float* __restrict__ b2v,
    const float* __restrict__ inp,
    unsigned short* __restrict__ H0a, unsigned short* __restrict__ H0b,
    unsigned short* __restrict__ H1a, unsigned short* __restrict__ H1b,
    unsigned* __restrict__ bar0, float* __restrict__ pred)
{
    const int tid = threadIdx.x;
    const int wv = tid >> 6, lane = tid & 63;
    const int blk = blockIdx.x;
    const int bg = blk & 1, rb = blk >> 1;
    const int bl = tid & 31, u = tid >> 5;
    const int mtl = bl >> 4, m16 = bl & 15;
    unsigned* dom = bar0 + (bg << 13);      // 32KB per barrier domain

    __shared__ float red1[32 * 272];        // 34.8KB: P2 reduce [half(2)][wv][m][ot]
    __shared__ float red2[16 * 272];        // 17KB: P1 reduce (crosses barrier B)
    __shared__ float red3[16 * 272];        // 17KB: P3 reduce
    __shared__ float h2x[32 * 9];
    __shared__ ull hstage[32][2];

    for (int i = tid; i < 32 * 9; i += 256) h2x[i] = 0.f;
    for (int i = tid; i < 16 * 272; i += 256) red1[16 * 272 + i] = 0.f;  // h1(-1)=0 part

    // ---- weights -> registers (read once) ----
    short8 Wr0[2][8], Wr1h0[2][8], Wr1h1[2][8], Wr2[2][8];
    {
        const short8* p0 = (const short8*)Wp0;
        const short8* p1 = (const short8*)Wp1;
        const short8* p2 = (const short8*)Wp2;
        #pragma unroll
        for (int ot = 0; ot < 2; ++ot)
            #pragma unroll
            for (int kk = 0; kk < 8; ++kk) {
                Wr0[ot][kk]   = p0[((rb * 2 + ot) * KS0 + 8 * wv + kk) * 64 + lane];
                Wr1h0[ot][kk] = p1[((rb * 2 + ot) * KS1 + 8 * wv + kk) * 64 + lane];
                Wr1h1[ot][kk] = p1[((rb * 2 + ot) * KS1 + 32 + 8 * wv + kk) * 64 + lane];
                Wr2[ot][kk]   = p2[(ot * KS0 + 8 * wv + kk) * 64 + lane];
            }
    }
    float wih0r[4][8], whh2r[4][8], b0r[4], b1r[4], b2r[4];
    #pragma unroll
    for (int g = 0; g < 4; ++g) {
        int row = rb * 8 + u + 1024 * g;
        #pragma unroll
        for (int d = 0; d < 8; ++d) wih0r[g][d] = wih0[row * 8 + d];
        b0r[g] = b0v[row];
        b1r[g] = b1v[row];
        int row2 = u + 8 * g;
        #pragma unroll
        for (int d = 0; d < 8; ++d) whh2r[g][d] = whh2[row2 * 8 + d];
        b2r[g] = b2v[row2];
    }
    float c0r = 0.f, c1r = 0.f, c2r = 0.f;
    unsigned ep = 0;
    __syncthreads();

    // tile set: idx = ((halfbase + wv)*2 + m)*2 + ot ; swizzled 17-stride layout
    auto redWrite = [&](float* red, f32x4 (&acc)[2][2], int halfbase) {
        #pragma unroll
        for (int m = 0; m < 2; ++m)
            #pragma unroll
            for (int ot = 0; ot < 2; ++ot) {
                int base = (((halfbase + wv) * 2 + m) * 2 + ot) * 272
                         + (lane & 15) * 17 + (lane >> 4) * 4;
                #pragma unroll
                for (int r = 0; r < 4; ++r) red[base + r] = acc[m][ot][r];
            }
    };
    auto redSum4 = [&](const float* red, int g) {
        int rr = u * 4 + g, ot = rr >> 4, rr16 = rr & 15;
        float s = 0.f;
        #pragma unroll
        for (int w2 = 0; w2 < 4; ++w2)
            s += red[((w2 * 2 + mtl) * 2 + ot) * 272 + rr16 * 17 + m16];
        return s;
    };
    auto redSum8 = [&](const float* red, int g) {
        int rr = u * 4 + g, ot = rr >> 4, rr16 = rr & 15;
        float s = 0.f;
        #pragma unroll
        for (int q = 0; q < 8; ++q)
            s += red[((q * 2 + mtl) * 2 + ot) * 272 + rr16 * 17 + m16];
        return s;
    };
    auto hPublish = [&](unsigned short* Hw) {
        __syncthreads();
        if (tid < 32) {
            int b = bg * 32 + tid;
            int chunk = ((b >> 4) * KS0 + (rb >> 2)) * 64 + ((b & 15) | ((rb & 3) << 4));
            cstore8((ull*)Hw + chunk * 2,     hstage[tid][0]);
            cstore8((ull*)Hw + chunk * 2 + 1, hstage[tid][1]);
        }
    };

    // ---- preamble: P1(0) (h0(-1)=0 -> GEMM term vanishes) ----
    {
        float xv[8];
        int b = bg * 32 + bl;
        #pragma unroll
        for (int d = 0; d < 8; ++d) xv[d] = inp[(b * TT + 0) * DD + d];
        float g4[4];
        #pragma unroll
        for (int g = 0; g < 4; ++g) {
            float s = b0r[g];
            #pragma unroll
            for (int d = 0; d < 8; ++d) s += wih0r[g][d] * xv[d];
            g4[g] = s;
        }
        c0r = sigm(g4[0]) * ftanh(g4[2]);
        float hn = sigm(g4[3]) * ftanh(c0r);
        ((unsigned short*)hstage)[bl * 8 + u] = f2bf(hn);
        hPublish(H0a);                               // h0(0)
    }
    gbar(dom, rb, ++ep);

    short8 pa[8], pb[8];

    for (int t = 0; t < NSTEP; ++t) {
        const int par = t & 1;
        const unsigned short* H0cur = par ? H0b : H0a;   // h0(t)
        unsigned short* H1w = par ? H1b : H1a;           // h1(t) dest
        unsigned short* H0nxt = par ? H0a : H0b;         // h0(t+1) dest
        const bool last = (t == NSTEP - 1);

        // ===================== window A->B =====================
        {
            // load h0(t) wave-quarter ONCE (16 cloads) -> feeds 2 GEMMs
            #pragma unroll
            for (int kk = 0; kk < 8; ++kk) {
                pa[kk] = cload(H0cur + (((bg * 2 + 0) * KS0 + 8 * wv + kk) * 64 + lane) * 8);
                pb[kk] = cload(H0cur + (((bg * 2 + 1) * KS0 + 8 * wv + kk) * 64 + lane) * 8);
            }
            f32x4 aP2[2][2], aP1[2][2];
            #pragma unroll
            for (int m = 0; m < 2; ++m)
                #pragma unroll
                for (int ot = 0; ot < 2; ++ot) {
                    aP2[m][ot] = (f32x4){0.f, 0.f, 0.f, 0.f};
                    aP1[m][ot] = (f32x4){0.f, 0.f, 0.f, 0.f};
                }
            #pragma unroll
            for (int kk = 0; kk < 8; ++kk) {
                #pragma unroll
                for (int ot = 0; ot < 2; ++ot) {
                    aP2[0][ot] = __builtin_amdgcn_mfma_f32_16x16x32_bf16(pa[kk], Wr1h0[ot][kk], aP2[0][ot], 0, 0, 0);
                    aP2[1][ot] = __builtin_amdgcn_mfma_f32_16x16x32_bf16(pb[kk], Wr1h0[ot][kk], aP2[1][ot], 0, 0, 0);
                    aP1[0][ot] = __builtin_amdgcn_mfma_f32_16x16x32_bf16(pa[kk], Wr0[ot][kk],   aP1[0][ot], 0, 0, 0);
                    aP1[1][ot] = __builtin_amdgcn_mfma_f32_16x16x32_bf16(pb[kk], Wr0[ot][kk],   aP1[1][ot], 0, 0, 0);
                }
            }
            redWrite(red1, aP2, 0);      // h0 contribution (this window)
            redWrite(red2, aP1, 0);      // P1(t+1) partials (read after barrier B)
            __syncthreads();
            // P2 cell: 8-way reduce (h0 part + h1 part parked last window)
            float g4[4];
            #pragma unroll
            for (int g = 0; g < 4; ++g) g4[g] = b1r[g] + redSum8(red1, g);
            c1r = sigm(g4[1]) * c1r + sigm(g4[0]) * ftanh(g4[2]);
            float hn = sigm(g4[3]) * ftanh(c1r);
            ((unsigned short*)hstage)[bl * 8 + u] = f2bf(hn);
            hPublish(H1w);                               // h1(t)
        }
        gbar(dom, rb, ++ep);    // barrier B

        // ===================== window B->A =====================
        {
            // load h1(t) wave-quarter ONCE -> feeds P3 + next step's P2-h1 part
            #pragma unroll
            for (int kk = 0; kk < 8; ++kk) {
                pa[kk] = cload(H1w + (((bg * 2 + 0) * KS0 + 8 * wv + kk) * 64 + lane) * 8);
                pb[kk] = cload(H1w + (((bg * 2 + 1) * KS0 + 8 * wv + kk) * 64 + lane) * 8);
            }
            f32x4 aP3[2][2], aN[2][2];
            #pragma unroll
            for (int m = 0; m < 2; ++m)
                #pragma unroll
                for (int ot = 0; ot < 2; ++ot) {
                    aP3[m][ot] = (f32x4){0.f, 0.f, 0.f, 0.f};
                    aN[m][ot]  = (f32x4){0.f, 0.f, 0.f, 0.f};
                }
            #pragma unroll
            for (int kk = 0; kk < 8; ++kk) {
                #pragma unroll
                for (int ot = 0; ot < 2; ++ot) {
                    aP3[0][ot] = __builtin_amdgcn_mfma_f32_16x16x32_bf16(pa[kk], Wr2[ot][kk],   aP3[0][ot], 0, 0, 0);
                    aP3[1][ot] = __builtin_amdgcn_mfma_f32_16x16x32_bf16(pb[kk], Wr2[ot][kk],   aP3[1][ot], 0, 0, 0);
                    aN[0][ot]  = __builtin_amdgcn_mfma_f32_16x16x32_bf16(pa[kk], Wr1h1[ot][kk], aN[0][ot], 0, 0, 0);
                    aN[1][ot]  = __builtin_amdgcn_mfma_f32_16x16x32_bf16(pb[kk], Wr1h1[ot][kk], aN[1][ot], 0, 0, 0);
                }
            }
            redWrite(red3, aP3, 0);
            __syncthreads();
            // P3 cell
            float xo[8];
            #pragma unroll
            for (int d = 0; d < 8; ++d) xo[d] = h2x[bl * 9 + d];
            float g4[4];
            #pragma unroll
            for (int g = 0; g < 4; ++g) {
                float s = b2r[g] + redSum4(red3, g);
                #pragma unroll
                for (int d = 0; d < 8; ++d) s += whh2r[g][d] * xo[d];
                g4[g] = s;
            }
            float cn = sigm(g4[1]) * c2r + sigm(g4[0]) * ftanh(g4[2]);
            c2r = cn;
            float hn2 = sigm(g4[3]) * ftanh(cn);
            __syncthreads();            // old-h2x reads done before overwrite
            h2x[bl * 9 + u] = hn2;
            if (rb == 0 && t >= ENC - 1)
                pred[((bg * 32 + bl) * HOR + (t - (ENC - 1))) * DD + u] = hn2;

            if (!last) {
                __syncthreads();        // h2x(t) visible
                // P1(t+1) cell
                const int tt = t + 1;
                float xv[8];
                if (tt < ENC) {
                    int b = bg * 32 + bl;
                    #pragma unroll
                    for (int d = 0; d < 8; ++d) xv[d] = inp[(b * TT + tt) * DD + d];
                } else {
                    #pragma unroll
                    for (int d = 0; d < 8; ++d) xv[d] = h2x[bl * 9 + d];
                }
                float g1[4];
                #pragma unroll
                for (int g = 0; g < 4; ++g) {
                    float s = b0r[g] + redSum4(red2, g);
                    #pragma unroll
                    for (int d = 0; d < 8; ++d) s += wih0r[g][d] * xv[d];
                    g1[g] = s;
                }
                c0r = sigm(g1[1]) * c0r + sigm(g1[0]) * ftanh(g1[2]);
                float hn0 = sigm(g1[3]) * ftanh(c0r);
                ((unsigned short*)hstage)[bl * 8 + u] = f2bf(hn0);
                hPublish(H0nxt);                          // h0(t+1)
                redWrite(red1, aN, 4);  // park h1 part for P2(t+1) (off crit path)
                gbar(dom, rb, ++ep);    // barrier A
            }
        }
    }
}

// ---------------- host ----------------

extern "C" void kernel_launch(void* const* d_in, const int* in_sizes, int n_in,
                              void* d_out, int out_size, void* d_ws, size_t ws_size,
                              hipStream_t stream)
{
    const float* inp  = (const float*)d_in[0];
    const float* wih0 = (const float*)d_in[1];
    const float* whh0 = (const float*)d_in[2];
    const float* b0v  = (const float*)d_in[3];
    const float* wih1 = (const float*)d_in[4];
    const float* whh1 = (const float*)d_in[5];
    const float* b1v  = (const float*)d_in[6];
    const float* wih2 = (const float*)d_in[7];
    const float* whh2 = (const float*)d_in[8];
    const float* b2v  = (const float*)d_in[9];
    float* out = (float*)d_out;   // pred[172032] | y[172032] | loss[8]

    char* base = (char*)d_ws;
    size_t off = 0;
    auto carve = [&](size_t bytes) -> void* {
        void* p = base + off;
        off += (bytes + 255) & ~((size_t)255);
        return p;
    };
    unsigned short* Wp0 = (unsigned short*)carve((size_t)128 * 2 * KS0 * 64 * 8 * 2);
    unsigned short* Wp1 = (unsigned short*)carve((size_t)128 * 2 * KS1 * 64 * 8 * 2);
    unsigned short* Wp2 = (unsigned short*)carve((size_t)2 * KS0 * 64 * 8 * 2);
    size_t state_off = off;
    unsigned short* H0a = (unsigned short*)carve(B64 * H * 2);
    unsigned short* H0b = (unsigned short*)carve(B64 * H * 2);
    unsigned short* H1a = (unsigned short*)carve(B64 * H * 2);
    unsigned short* H1b = (unsigned short*)carve(B64 * H * 2);
    unsigned* bar = (unsigned*)carve(2 * 8192 * 4);   // 2 domains x 32KB
    size_t state_bytes = off - state_off;
    if (off > ws_size) return;

    zero_k<<<64, 256, 0, stream>>>((unsigned int*)(base + state_off), (int)(state_bytes / 4));
    pack0_k<<<2048, 256, 0, stream>>>(whh0, Wp0);
    pack1_k<<<4096, 256, 0, stream>>>(wih1, whh1, Wp1);
    pack2_k<<<32, 256, 0, stream>>>(wih2, Wp2);
    copy_y_k<<<672, 256, 0, stream>>>(inp, out + 172032);

    persist_k<<<NBLK, 256, 0, stream>>>(Wp0, Wp1, Wp2, wih0, b0v, b1v, whh2, b2v,
                                        inp, H0a, H0b, H1a, H1b, bar, out);

    loss_k<<<1, 256, 0, stream>>>(out, out + 172032, out + 344064);
}

// Round 10
// 3569.210 us; speedup vs baseline: 1.5773x; 1.5773x over previous
//
#include <hip/hip_runtime.h>
#include <math.h>

#define B64 64
#define H 1024
#define DD 8
#define ENC 96
#define HOR 336
#define TT 432
#define NSTEP 431
#define NBLK 256
#define KS0 32      // K=1024 in 32-wide chunks
#define KS1 64      // K=2048

typedef __attribute__((ext_vector_type(8))) short short8;
typedef __attribute__((ext_vector_type(4))) float f32x4;
typedef unsigned long long ull;

__device__ __forceinline__ unsigned short f2bf(float x) {
    union { float f; unsigned u; } v; v.f = x;
    unsigned r = v.u + 0x7fffu + ((v.u >> 16) & 1u);
    return (unsigned short)(r >> 16);
}
__device__ __forceinline__ float sigm(float x) {
    return __builtin_amdgcn_rcpf(1.0f + __expf(-x));
}
__device__ __forceinline__ float ftanh(float x) {
    float e = __expf(fminf(x, 10.0f) * 2.0f);   // clamp: avoid inf/inf
    return (e - 1.0f) * __builtin_amdgcn_rcpf(e + 1.0f);
}

// Agent-coherent (sc0 sc1, MALL-coherent, no cache-maintenance) accessors
__device__ __forceinline__ short8 cload(const unsigned short* p) {
    const ull* q = (const ull*)p;
    ull lo = __hip_atomic_load(q,     __ATOMIC_RELAXED, __HIP_MEMORY_SCOPE_AGENT);
    ull hi = __hip_atomic_load(q + 1, __ATOMIC_RELAXED, __HIP_MEMORY_SCOPE_AGENT);
    union { ull u[2]; short8 s; } v; v.u[0] = lo; v.u[1] = hi;
    return v.s;
}
__device__ __forceinline__ void cstore8(ull* p, ull v) {
    __hip_atomic_store(p, v, __ATOMIC_RELAXED, __HIP_MEMORY_SCOPE_AGENT);
}

// ---------------- prep kernels (verified) ----------------

__global__ void zero_k(unsigned int* __restrict__ p, int n) {
    for (int i = blockIdx.x * 256 + threadIdx.x; i < n; i += gridDim.x * 256) p[i] = 0u;
}

__global__ void pack0_k(const float* __restrict__ w, unsigned short* __restrict__ dst) {
    const int total = 128 * 2 * KS0 * 64 * 8;
    for (int idx = blockIdx.x * 256 + threadIdx.x; idx < total; idx += gridDim.x * 256) {
        int j = idx & 7, lane = (idx >> 3) & 63, ks = (idx >> 9) & 31, nt = (idx >> 14) & 1, nb = idx >> 15;
        int rr = nt * 16 + (lane & 15);
        int row = nb * 8 + (rr >> 2) + 1024 * (rr & 3);
        int k = ks * 32 + ((lane >> 4) << 3) + j;
        dst[idx] = f2bf(w[row * 1024 + k]);
    }
}

__global__ void pack1_k(const float* __restrict__ wih, const float* __restrict__ whh,
                        unsigned short* __restrict__ dst) {
    const int total = 128 * 2 * KS1 * 64 * 8;
    for (int idx = blockIdx.x * 256 + threadIdx.x; idx < total; idx += gridDim.x * 256) {
        int j = idx & 7, lane = (idx >> 3) & 63, ks = (idx >> 9) & 63, nt = (idx >> 15) & 1, nb = idx >> 16;
        int rr = nt * 16 + (lane & 15);
        int row = nb * 8 + (rr >> 2) + 1024 * (rr & 3);
        int k = ks * 32 + ((lane >> 4) << 3) + j;
        float v = (k < 1024) ? wih[row * 1024 + k] : whh[row * 1024 + (k - 1024)];
        dst[idx] = f2bf(v);
    }
}

__global__ void pack2_k(const float* __restrict__ w, unsigned short* __restrict__ dst) {
    const int total = 2 * KS0 * 64 * 8;
    for (int idx = blockIdx.x * 256 + threadIdx.x; idx < total; idx += gridDim.x * 256) {
        int j = idx & 7, lane = (idx >> 3) & 63, ks = (idx >> 9) & 31, nt = (idx >> 14) & 1;
        int rr = nt * 16 + (lane & 15);
        int row = (rr >> 2) + 8 * (rr & 3);
        int k = ks * 32 + ((lane >> 4) << 3) + j;
        dst[idx] = f2bf(w[row * 1024 + k]);
    }
}

__global__ void copy_y_k(const float* __restrict__ inp, float* __restrict__ y) {
    const int total = B64 * HOR * DD;
    for (int i = blockIdx.x * 256 + threadIdx.x; i < total; i += gridDim.x * 256) {
        int b = i / (HOR * DD);
        int rem = i - b * (HOR * DD);
        y[i] = inp[b * (TT * DD) + ENC * DD + rem];
    }
}

__global__ void loss_k(const float* __restrict__ pred, const float* __restrict__ y,
                       float* __restrict__ loss) {
    __shared__ float part[256];
    int tid = threadIdx.x;
    int dd = tid & 7, cc = tid >> 3;
    float s = 0.f;
    for (int i = cc; i < B64 * HOR; i += 32) {
        float d = pred[i * 8 + dd] - y[i * 8 + dd];
        s += d * d;
    }
    part[tid] = s;
    __syncthreads();
    if (tid < 8) {
        float t = 0.f;
        for (int r = 0; r < 32; ++r) t += part[r * 8 + tid];
        loss[tid] = t / (float)(B64 * HOR);
    }
}

// ---- split-phase grid barrier (system flags, all-sweep) ----
// arrive: tid0 drains its wave's stores (publish is wave-0-only) + flag store.
// wait: wave0 sweeps 128 flags; trailing __syncthreads releases the block.
__device__ __forceinline__ void gbar_arrive(unsigned* dom, int rb, unsigned ep) {
    if (threadIdx.x == 0) {
        __builtin_amdgcn_s_waitcnt(0x0f70);     // vmcnt(0)
        __hip_atomic_store(dom + rb * 32, ep, __ATOMIC_RELAXED,
                           __HIP_MEMORY_SCOPE_SYSTEM);
    }
}
__device__ __forceinline__ void gbar_wait(unsigned* dom, unsigned ep) {
    const int tid = threadIdx.x;
    if (tid < 64) {
        const unsigned* f0 = dom + tid * 32;
        const unsigned* f1 = dom + (tid + 64) * 32;
        for (;;) {
            unsigned a = __hip_atomic_load(f0, __ATOMIC_RELAXED, __HIP_MEMORY_SCOPE_SYSTEM);
            unsigned b = __hip_atomic_load(f1, __ATOMIC_RELAXED, __HIP_MEMORY_SCOPE_SYSTEM);
            if (__all((a >= ep) && (b >= ep))) break;
        }
    }
    __syncthreads();
}

// ---------------- persistent recurrence kernel ----------------
// Split-phase pipeline (per step, 2 barriers):
//  [gap A]  accP2 = MFMA(qa/qb = h1(t-1) frags kept in regs, Wr1h1)
//  wait A   -> h0(t) visible
//  window A: load pa/pb = h0(t) quarter; accP2 += MFMA(pa/pb, Wr1h0);
//            reduce; P2 cell -> publish h1(t); arrive B;
//  [gap B]  P1(t+1) GEMM on pa/pb -> red2
//  wait B   -> h1(t) visible
//  window B: load qa/qb = h1(t) quarter (kept for next gap A);
//            P3 GEMM (streamed Wr2) -> reduce; P3 cell -> h2x/pred;
//            P1 cell (red2 + wih0*x) -> publish h0(t+1); arrive A.
__global__ __launch_bounds__(256, 1) void persist_k(
    const unsigned short* __restrict__ Wp0,
    const unsigned short* __restrict__ Wp1,
    const unsigned short* __restrict__ Wp2,
    const float* __restrict__ wih0, const float* __restrict__ b0v,
    const float* __restrict__ b1v,
    const float* __restrict__ whh2, const float* __restrict__ b2v,
    const float* __restrict__ inp,
    unsigned short* __restrict__ H0a, unsigned short* __restrict__ H0b,
    unsigned short* __restrict__ H1a, unsigned short* __restrict__ H1b,
    unsigned* __restrict__ bar0, float* __restrict__ pred)
{
    const int tid = threadIdx.x;
    const int wv = tid >> 6, lane = tid & 63;
    const int blk = blockIdx.x;
    const int bg = blk & 1, rb = blk >> 1;
    const int bl = tid & 31, u = tid >> 5;
    const int mtl = bl >> 4, m16 = bl & 15;
    unsigned* dom = bar0 + (bg << 13);      // 32KB per barrier domain

    __shared__ float red1[16 * 272];        // 17KB (P2 then P3)
    __shared__ float red2[16 * 272];        // 17KB (P1, crosses barrier B)
    __shared__ float h2x[32 * 9];
    __shared__ ull hstage[32][2];

    for (int i = tid; i < 32 * 9; i += 256) h2x[i] = 0.f;

    // ---- resident weights (Wr2 streamed per step instead) ----
    short8 Wr0[2][8], Wr1h0[2][8], Wr1h1[2][8];
    {
        const short8* p0 = (const short8*)Wp0;
        const short8* p1 = (const short8*)Wp1;
        #pragma unroll
        for (int ot = 0; ot < 2; ++ot)
            #pragma unroll
            for (int kk = 0; kk < 8; ++kk) {
                Wr0[ot][kk]   = p0[((rb * 2 + ot) * KS0 + 8 * wv + kk) * 64 + lane];
                Wr1h0[ot][kk] = p1[((rb * 2 + ot) * KS1 + 8 * wv + kk) * 64 + lane];
                Wr1h1[ot][kk] = p1[((rb * 2 + ot) * KS1 + 32 + 8 * wv + kk) * 64 + lane];
            }
    }
    float wih0r[4][8], whh2r[4][8], b0r[4], b1r[4], b2r[4];
    #pragma unroll
    for (int g = 0; g < 4; ++g) {
        int row = rb * 8 + u + 1024 * g;
        #pragma unroll
        for (int d = 0; d < 8; ++d) wih0r[g][d] = wih0[row * 8 + d];
        b0r[g] = b0v[row];
        b1r[g] = b1v[row];
        int row2 = u + 8 * g;
        #pragma unroll
        for (int d = 0; d < 8; ++d) whh2r[g][d] = whh2[row2 * 8 + d];
        b2r[g] = b2v[row2];
    }
    float c0r = 0.f, c1r = 0.f, c2r = 0.f;
    unsigned ep = 0;

    auto redWrite = [&](float* red, f32x4 (&acc)[2][2]) {
        #pragma unroll
        for (int m = 0; m < 2; ++m)
            #pragma unroll
            for (int ot = 0; ot < 2; ++ot) {
                int base = ((wv * 2 + m) * 2 + ot) * 272 + (lane & 15) * 17 + (lane >> 4) * 4;
                #pragma unroll
                for (int r = 0; r < 4; ++r) red[base + r] = acc[m][ot][r];
            }
    };
    auto redSum = [&](const float* red, int g) {
        int rr = u * 4 + g, ot = rr >> 4, rr16 = rr & 15;
        float s = 0.f;
        #pragma unroll
        for (int w2 = 0; w2 < 4; ++w2)
            s += red[((w2 * 2 + mtl) * 2 + ot) * 272 + rr16 * 17 + m16];
        return s;
    };
    auto hPublish = [&](unsigned short* Hw) {
        __syncthreads();
        if (tid < 32) {
            int b = bg * 32 + tid;
            int chunk = ((b >> 4) * KS0 + (rb >> 2)) * 64 + ((b & 15) | ((rb & 3) << 4));
            cstore8((ull*)Hw + chunk * 2,     hstage[tid][0]);
            cstore8((ull*)Hw + chunk * 2 + 1, hstage[tid][1]);
        }
    };

    // qa/qb carry h1 fragments across the A barrier; zero = h1(-1)
    short8 qa[8], qb[8];
    {
        union { ull u[2]; short8 s; } z; z.u[0] = 0; z.u[1] = 0;
        #pragma unroll
        for (int kk = 0; kk < 8; ++kk) { qa[kk] = z.s; qb[kk] = z.s; }
    }
    __syncthreads();

    // ---- preamble: P1(0) (h0(-1)=0 -> GEMM term vanishes) ----
    {
        float xv[8];
        int b = bg * 32 + bl;
        #pragma unroll
        for (int d = 0; d < 8; ++d) xv[d] = inp[(b * TT + 0) * DD + d];
        float g4[4];
        #pragma unroll
        for (int g = 0; g < 4; ++g) {
            float s = b0r[g];
            #pragma unroll
            for (int d = 0; d < 8; ++d) s += wih0r[g][d] * xv[d];
            g4[g] = s;
        }
        c0r = sigm(g4[0]) * ftanh(g4[2]);
        float hn = sigm(g4[3]) * ftanh(c0r);
        ((unsigned short*)hstage)[bl * 8 + u] = f2bf(hn);
        hPublish(H0a);                               // h0(0)
    }
    gbar_arrive(dom, rb, ++ep);

    short8 pa[8], pb[8];

    for (int t = 0; t < NSTEP; ++t) {
        const int par = t & 1;
        const unsigned short* H0cur = par ? H0b : H0a;   // h0(t)
        unsigned short* H1w = par ? H1b : H1a;           // h1(t) dest
        unsigned short* H0nxt = par ? H0a : H0b;         // h0(t+1) dest
        const bool last = (t == NSTEP - 1);

        // ---- gap A: P2's h1(t-1) half from carried qa/qb (pure VALU/MFMA) ----
        f32x4 acc[2][2];
        #pragma unroll
        for (int m = 0; m < 2; ++m)
            #pragma unroll
            for (int ot = 0; ot < 2; ++ot) acc[m][ot] = (f32x4){0.f, 0.f, 0.f, 0.f};
        #pragma unroll
        for (int kk = 0; kk < 8; ++kk) {
            #pragma unroll
            for (int ot = 0; ot < 2; ++ot) {
                acc[0][ot] = __builtin_amdgcn_mfma_f32_16x16x32_bf16(qa[kk], Wr1h1[ot][kk], acc[0][ot], 0, 0, 0);
                acc[1][ot] = __builtin_amdgcn_mfma_f32_16x16x32_bf16(qb[kk], Wr1h1[ot][kk], acc[1][ot], 0, 0, 0);
            }
        }
        gbar_wait(dom, ep);                  // wait A: h0(t) visible

        // ================= window A =================
        {
            #pragma unroll
            for (int kk = 0; kk < 8; ++kk) {
                pa[kk] = cload(H0cur + (((bg * 2 + 0) * KS0 + 8 * wv + kk) * 64 + lane) * 8);
                pb[kk] = cload(H0cur + (((bg * 2 + 1) * KS0 + 8 * wv + kk) * 64 + lane) * 8);
            }
            #pragma unroll
            for (int kk = 0; kk < 8; ++kk) {
                #pragma unroll
                for (int ot = 0; ot < 2; ++ot) {
                    acc[0][ot] = __builtin_amdgcn_mfma_f32_16x16x32_bf16(pa[kk], Wr1h0[ot][kk], acc[0][ot], 0, 0, 0);
                    acc[1][ot] = __builtin_amdgcn_mfma_f32_16x16x32_bf16(pb[kk], Wr1h0[ot][kk], acc[1][ot], 0, 0, 0);
                }
            }
            redWrite(red1, acc);
            __syncthreads();
            float g4[4];
            #pragma unroll
            for (int g = 0; g < 4; ++g) g4[g] = b1r[g] + redSum(red1, g);
            c1r = sigm(g4[1]) * c1r + sigm(g4[0]) * ftanh(g4[2]);
            float hn = sigm(g4[3]) * ftanh(c1r);
            ((unsigned short*)hstage)[bl * 8 + u] = f2bf(hn);
            hPublish(H1w);                               // h1(t)
        }
        gbar_arrive(dom, rb, ++ep);          // arrive B

        // ---- gap B: P1(t+1) GEMM on pa/pb (h0(t)) ----
        if (!last) {
            f32x4 a1[2][2];
            #pragma unroll
            for (int m = 0; m < 2; ++m)
                #pragma unroll
                for (int ot = 0; ot < 2; ++ot) a1[m][ot] = (f32x4){0.f, 0.f, 0.f, 0.f};
            #pragma unroll
            for (int kk = 0; kk < 8; ++kk) {
                #pragma unroll
                for (int ot = 0; ot < 2; ++ot) {
                    a1[0][ot] = __builtin_amdgcn_mfma_f32_16x16x32_bf16(pa[kk], Wr0[ot][kk], a1[0][ot], 0, 0, 0);
                    a1[1][ot] = __builtin_amdgcn_mfma_f32_16x16x32_bf16(pb[kk], Wr0[ot][kk], a1[1][ot], 0, 0, 0);
                }
            }
            redWrite(red2, a1);
        }
        gbar_wait(dom, ep);                  // wait B: h1(t) visible

        // ================= window B =================
        {
            // stream Wr2 (L1/L2-cached, immutable) alongside the h1 cloads
            const short8* p2w = (const short8*)Wp2;
            short8 w2[2][8];
            #pragma unroll
            for (int ot = 0; ot < 2; ++ot)
                #pragma unroll
                for (int kk = 0; kk < 8; ++kk)
                    w2[ot][kk] = p2w[(ot * KS0 + 8 * wv + kk) * 64 + lane];
            #pragma unroll
            for (int kk = 0; kk < 8; ++kk) {
                qa[kk] = cload(H1w + (((bg * 2 + 0) * KS0 + 8 * wv + kk) * 64 + lane) * 8);
                qb[kk] = cload(H1w + (((bg * 2 + 1) * KS0 + 8 * wv + kk) * 64 + lane) * 8);
            }
            f32x4 a3[2][2];
            #pragma unroll
            for (int m = 0; m < 2; ++m)
                #pragma unroll
                for (int ot = 0; ot < 2; ++ot) a3[m][ot] = (f32x4){0.f, 0.f, 0.f, 0.f};
            #pragma unroll
            for (int kk = 0; kk < 8; ++kk) {
                #pragma unroll
                for (int ot = 0; ot < 2; ++ot) {
                    a3[0][ot] = __builtin_amdgcn_mfma_f32_16x16x32_bf16(qa[kk], w2[ot][kk], a3[0][ot], 0, 0, 0);
                    a3[1][ot] = __builtin_amdgcn_mfma_f32_16x16x32_bf16(qb[kk], w2[ot][kk], a3[1][ot], 0, 0, 0);
                }
            }
            redWrite(red1, a3);             // red1 last read pre-barrier-B
            __syncthreads();
            // P3 cell
            float xo[8];
            #pragma unroll
            for (int d = 0; d < 8; ++d) xo[d] = h2x[bl * 9 + d];
            float g4[4];
            #pragma unroll
            for (int g = 0; g < 4; ++g) {
                float s = b2r[g] + redSum(red1, g);
                #pragma unroll
                for (int d = 0; d < 8; ++d) s += whh2r[g][d] * xo[d];
                g4[g] = s;
            }
            float cn = sigm(g4[1]) * c2r + sigm(g4[0]) * ftanh(g4[2]);
            c2r = cn;
            float hn2 = sigm(g4[3]) * ftanh(cn);
            __syncthreads();                // old-h2x reads done
            h2x[bl * 9 + u] = hn2;
            if (rb == 0 && t >= ENC - 1)
                pred[((bg * 32 + bl) * HOR + (t - (ENC - 1))) * DD + u] = hn2;

            if (!last) {
                __syncthreads();            // h2x(t) visible
                const int tt = t + 1;
                float xv[8];
                if (tt < ENC) {
                    int b = bg * 32 + bl;
                    #pragma unroll
                    for (int d = 0; d < 8; ++d) xv[d] = inp[(b * TT + tt) * DD + d];
                } else {
                    #pragma unroll
                    for (int d = 0; d < 8; ++d) xv[d] = h2x[bl * 9 + d];
                }
                float g1[4];
                #pragma unroll
                for (int g = 0; g < 4; ++g) {
                    float s = b0r[g] + redSum(red2, g);
                    #pragma unroll
                    for (int d = 0; d < 8; ++d) s += wih0r[g][d] * xv[d];
                    g1[g] = s;
                }
                c0r = sigm(g1[1]) * c0r + sigm(g1[0]) * ftanh(g1[2]);
                float hn0 = sigm(g1[3]) * ftanh(c0r);
                ((unsigned short*)hstage)[bl * 8 + u] = f2bf(hn0);
                hPublish(H0nxt);                          // h0(t+1)
                gbar_arrive(dom, rb, ++ep);               // arrive A
                // loop head's gap-A MFMA runs before wait A
            }
        }
    }
}

// ---------------- host ----------------

extern "C" void kernel_launch(void* const* d_in, const int* in_sizes, int n_in,
                              void* d_out, int out_size, void* d_ws, size_t ws_size,
                              hipStream_t stream)
{
    const float* inp  = (const float*)d_in[0];
    const float* wih0 = (const float*)d_in[1];
    const float* whh0 = (const float*)d_in[2];
    const float* b0v  = (const float*)d_in[3];
    const float* wih1 = (const float*)d_in[4];
    const float* whh1 = (const float*)d_in[5];
    const float* b1v  = (const float*)d_in[6];
    const float* wih2 = (const float*)d_in[7];
    const float* whh2 = (const float*)d_in[8];
    const float* b2v  = (const float*)d_in[9];
    float* out = (float*)d_out;   // pred[172032] | y[172032] | loss[8]

    char* base = (char*)d_ws;
    size_t off = 0;
    auto carve = [&](size_t bytes) -> void* {
        void* p = base + off;
        off += (bytes + 255) & ~((size_t)255);
        return p;
    };
    unsigned short* Wp0 = (unsigned short*)carve((size_t)128 * 2 * KS0 * 64 * 8 * 2);
    unsigned short* Wp1 = (unsigned short*)carve((size_t)128 * 2 * KS1 * 64 * 8 * 2);
    unsigned short* Wp2 = (unsigned short*)carve((size_t)2 * KS0 * 64 * 8 * 2);
    size_t state_off = off;
    unsigned short* H0a = (unsigned short*)carve(B64 * H * 2);
    unsigned short* H0b = (unsigned short*)carve(B64 * H * 2);
    unsigned short* H1a = (unsigned short*)carve(B64 * H * 2);
    unsigned short* H1b = (unsigned short*)carve(B64 * H * 2);
    unsigned* bar = (unsigned*)carve(2 * 8192 * 4);   // 2 domains x 32KB
    size_t state_bytes = off - state_off;
    if (off > ws_size) return;

    zero_k<<<64, 256, 0, stream>>>((unsigned int*)(base + state_off), (int)(state_bytes / 4));
    pack0_k<<<2048, 256, 0, stream>>>(whh0, Wp0);
    pack1_k<<<4096, 256, 0, stream>>>(wih1, whh1, Wp1);
    pack2_k<<<32, 256, 0, stream>>>(wih2, Wp2);
    copy_y_k<<<672, 256, 0, stream>>>(inp, out + 172032);

    persist_k<<<NBLK, 256, 0, stream>>>(Wp0, Wp1, Wp2, wih0, b0v, b1v, whh2, b2v,
                                        inp, H0a, H0b, H1a, H1b, bar, out);

    loss_k<<<1, 256, 0, stream>>>(out, out + 172032, out + 344064);
}